// Round 6
// baseline (1247.872 us; speedup 1.0000x reference)
//
#include <hip/hip_runtime.h>
#include <stdint.h>

#define AS1 __attribute__((address_space(1)))
#define AS3 __attribute__((address_space(3)))

using bf16x8 = __attribute__((ext_vector_type(8))) short;
using f32x4  = __attribute__((ext_vector_type(4))) float;

// ---- helpers -------------------------------------------------------------
__device__ __forceinline__ unsigned short f2bf(float f) {
  union { float f; unsigned u; } v; v.f = f;
  return (unsigned short)((v.u + 0x7FFFu + ((v.u >> 16) & 1u)) >> 16); // RNE
}
__device__ __forceinline__ float bf2f(unsigned short h) {
  union { unsigned u; float f; } v; v.u = ((unsigned)h) << 16;
  return v.f;
}
// async global->LDS, 16B per lane; lds dest must be wave-uniform base (HW adds lane*16)
__device__ __forceinline__ void gload_lds16(const void* g, void* l) {
  __builtin_amdgcn_global_load_lds((AS1 const void*)g, (AS3 void*)l, 16, 0, 0);
}

// ---- fused fp32 -> bf16 convert for x + 4 weights (one launch) ------------
// totals: x = 2,097,152 float4; each weight = 1,048,576 float4; sum = 6,291,456
__global__ void k_cvt5(const float* __restrict__ x,  const float* __restrict__ wq,
                       const float* __restrict__ wk, const float* __restrict__ wv,
                       const float* __restrict__ wo,
                       unsigned short* __restrict__ xb,  unsigned short* __restrict__ wqb,
                       unsigned short* __restrict__ wkb, unsigned short* __restrict__ wvb,
                       unsigned short* __restrict__ wob) {
  int idx = blockIdx.x * blockDim.x + threadIdx.x;
  int stride = gridDim.x * blockDim.x;
  for (int i = idx; i < 6291456; i += stride) {
    const float* src; unsigned short* dst; int off;
    if (i < 2097152) { src = x; dst = xb; off = i; }
    else {
      int j = i - 2097152;
      int w = j >> 20;            // 1,048,576 float4 per weight
      off = j & 1048575;
      src = (w == 0) ? wq : (w == 1) ? wk : (w == 2) ? wv : wo;
      dst = (w == 0) ? wqb : (w == 1) ? wkb : (w == 2) ? wvb : wob;
    }
    float4 f = ((const float4*)src)[off];
    ushort4 o;
    o.x = f2bf(f.x); o.y = f2bf(f.y); o.z = f2bf(f.z); o.w = f2bf(f.w);
    ((ushort4*)dst)[off] = o;
  }
}

// ---- RoPE tables: cos/sin[t][i], i in [0,64) ------------------------------
__global__ void k_rope_tables(float* __restrict__ ct, float* __restrict__ st) {
  int idx = blockIdx.x * blockDim.x + threadIdx.x; // T*64 threads
  int t = idx >> 6, i = idx & 63;
  float invf = exp2f(-(float)i * (13.287712379549449f / 64.0f));
  float a = (float)t * invf;
  ct[idx] = cosf(a);
  st[idx] = sinf(a);
}

// ---- RoPE apply in-place on q and k [BH, T, 128] bf16 ---------------------
// q additionally pre-scaled by (1/sqrt(128))*log2(e) so flash logits are
// already base-2 (kills the per-step scale multiply in k_flash).
__global__ void k_rope(unsigned short* __restrict__ q, unsigned short* __restrict__ k,
                       const float* __restrict__ ct, const float* __restrict__ st) {
  const float SC2 = 0.12751659974141322f;
  int idx = blockIdx.x * blockDim.x + threadIdx.x; // B*H*T*64 threads
  int i = idx & 63;
  int t = (idx >> 6) & 2047;
  int bh = idx >> 17;
  size_t base = ((size_t)bh * 2048 + t) * 128;
  float c = ct[t * 64 + i], s = st[t * 64 + i];
  {
    float x1 = bf2f(q[base + i]), x2 = bf2f(q[base + i + 64]);
    q[base + i]      = f2bf((x1 * c - x2 * s) * SC2);
    q[base + i + 64] = f2bf((x2 * c + x1 * s) * SC2);
  }
  {
    float x1 = bf2f(k[base + i]), x2 = bf2f(k[base + i + 64]);
    k[base + i]      = f2bf(x1 * c - x2 * s);
    k[base + i + 64] = f2bf(x2 * c + x1 * s);
  }
}

// ---- GEMM: C = A @ B^T. A:[M,K] bf16 rowmajor, Bw:[N,K] bf16 rowmajor.
// MODE 0: f32 out [M,N]
// MODE 1: bf16 out at [b,h,t,d]  -> Q/K layout
// MODE 2: bf16 out at [b,h,d,t]  -> transposed V layout
template <int MODE>
__global__ __launch_bounds__(256) void k_gemm(const unsigned short* __restrict__ A,
                                              const unsigned short* __restrict__ Bw,
                                              void* __restrict__ Cout,
                                              int M, int N, int K) {
  __shared__ __align__(16) unsigned short As[128 * 64];
  __shared__ __align__(16) unsigned short Bs[128 * 64];

  const int tid = threadIdx.x;
  const int wid = tid >> 6, lane = tid & 63;
  const int wm = wid >> 1, wn = wid & 1;
  const int m0 = blockIdx.y * 128, n0 = blockIdx.x * 128;
  const int rowA = lane & 15;
  const int kgrp = (lane >> 4) * 8;
  const int rgrp = (lane >> 4) * 4;
  const int srow = lane >> 3;
  const int scol = (lane & 7) * 8;

  f32x4 acc[4][4];
  const f32x4 z4 = {0.f, 0.f, 0.f, 0.f};
#pragma unroll
  for (int i = 0; i < 4; ++i)
#pragma unroll
    for (int j = 0; j < 4; ++j) acc[i][j] = z4;

  for (int k0 = 0; k0 < K; k0 += 64) {
    __syncthreads();
#pragma unroll
    for (int i = 0; i < 4; ++i) {
      int c = wid * 4 + i;
      const unsigned short* ga = A  + (size_t)(m0 + c * 8 + srow) * K + k0 + scol;
      gload_lds16(ga, (void*)&As[c * 512]);
      const unsigned short* gb = Bw + (size_t)(n0 + c * 8 + srow) * K + k0 + scol;
      gload_lds16(gb, (void*)&Bs[c * 512]);
    }
    __syncthreads();
#pragma unroll
    for (int kk = 0; kk < 64; kk += 32) {
      bf16x8 af[4], bfv[4];
#pragma unroll
      for (int i = 0; i < 4; ++i)
        af[i] = *(const bf16x8*)&As[(wm * 64 + i * 16 + rowA) * 64 + kk + kgrp];
#pragma unroll
      for (int j = 0; j < 4; ++j)
        bfv[j] = *(const bf16x8*)&Bs[(wn * 64 + j * 16 + rowA) * 64 + kk + kgrp];
#pragma unroll
      for (int i = 0; i < 4; ++i)
#pragma unroll
        for (int j = 0; j < 4; ++j)
          acc[i][j] = __builtin_amdgcn_mfma_f32_16x16x32_bf16(af[i], bfv[j], acc[i][j], 0, 0, 0);
    }
  }

#pragma unroll
  for (int i = 0; i < 4; ++i) {
#pragma unroll
    for (int j = 0; j < 4; ++j) {
      if (MODE == 2) {
        int gn = n0 + wn * 64 + j * 16 + rowA;
        int h = gn >> 7, d = gn & 127;
        int gmb = m0 + wm * 64 + i * 16 + rgrp;
        int b = gmb >> 11, t = gmb & 2047;
        ushort4 pk;
        pk.x = f2bf(acc[i][j][0]); pk.y = f2bf(acc[i][j][1]);
        pk.z = f2bf(acc[i][j][2]); pk.w = f2bf(acc[i][j][3]);
        *(ushort4*)&((unsigned short*)Cout)[(((size_t)(b * 16 + h)) * 128 + d) * 2048 + t] = pk;
      } else {
#pragma unroll
        for (int r = 0; r < 4; ++r) {
          int gm = m0 + wm * 64 + i * 16 + rgrp + r;
          int gn = n0 + wn * 64 + j * 16 + rowA;
          float v = acc[i][j][r];
          if (MODE == 0) {
            ((float*)Cout)[(size_t)gm * N + gn] = v;
          } else {
            int b = gm >> 11, t = gm & 2047;
            int h = gn >> 7, d = gn & 127;
            ((unsigned short*)Cout)[(((size_t)(b * 16 + h)) * 2048 + t) * 128 + d] = f2bf(v);
          }
        }
      }
    }
  }
}

// ---- flash attention fwd: ONE WAVE per block, 32 q rows, 64-wide KV tiles
// Pipelined: K loaded in halves (next tile's first half prefetched during PV),
// V issued post-QK and consumed post-softmax, causal mask hoisted to last tile,
// Q pre-scaled at RoPE (logits already base-2). K/V L2-resident (4 heads/XCD).
__global__ void k_flash(const unsigned short* __restrict__ q,
                        const unsigned short* __restrict__ k,
                        const unsigned short* __restrict__ vt,
                        unsigned short* __restrict__ obt) {
  __shared__ __align__(16) unsigned short Plds[32 * 64]; // 4KB, XOR-swizzled

  const int lane = threadIdx.x;
  const int rowA = lane & 15, kgrp = (lane >> 4) * 8, rgrp = (lane >> 4) * 4;
  const int bid = blockIdx.x;
  const int xcd = bid & 7;            // round-robin XCD dispatch assumption (perf-only)
  const int r0  = bid >> 3;
  const int bh  = xcd * 4 + (r0 & 3); // 4 heads per XCD: K+V = 4MB = one L2
  const int j   = 63 - (r0 >> 2);     // heavy q-tiles dispatch first
  const int q0  = j * 32;
  const int b = bh >> 4, h = bh & 15;

  const unsigned short* qh  = q  + (size_t)bh * 2048 * 128;
  const unsigned short* kh  = k  + (size_t)bh * 2048 * 128;
  const unsigned short* vth = vt + (size_t)bh * 128 * 2048;

  bf16x8 qf[2][4];
#pragma unroll
  for (int m = 0; m < 2; ++m)
#pragma unroll
    for (int kq = 0; kq < 4; ++kq)
      qf[m][kq] = *(const bf16x8*)(qh + (size_t)(q0 + m * 16 + rowA) * 128 + kq * 32 + kgrp);

  const f32x4 z4 = {0.f, 0.f, 0.f, 0.f};
  f32x4 o[2][8];
  float mprev[2][4], lsum[2][4];
#pragma unroll
  for (int m = 0; m < 2; ++m) {
#pragma unroll
    for (int dn = 0; dn < 8; ++dn) o[m][dn] = z4;
#pragma unroll
    for (int r = 0; r < 4; ++r) { mprev[m][r] = -1e30f; lsum[m][r] = 0.f; }
  }

  const int nt = (q0 >> 6) + 1; // 64-wide tiles; only last needs mask

  // K fragments in halves: ka = kq 0..1, kb = kq 2..3 (each 8 frags, 32 VGPR)
  bf16x8 ka[2][4], kb[2][4];
#pragma unroll
  for (int kq = 0; kq < 2; ++kq)
#pragma unroll
    for (int n = 0; n < 4; ++n)
      ka[kq][n] = *(const bf16x8*)(kh + (size_t)(n * 16 + rowA) * 128 + kq * 32 + kgrp);

  for (int it = 0; it < nt; ++it) {
    const int kv0 = it * 64;

    // second K half for this tile (covered by first-half QK below)
#pragma unroll
    for (int kq = 0; kq < 2; ++kq)
#pragma unroll
      for (int n = 0; n < 4; ++n)
        kb[kq][n] = *(const bf16x8*)(kh + (size_t)(kv0 + n * 16 + rowA) * 128 + (kq + 2) * 32 + kgrp);

    // ---- S = Q K^T (logits already base-2-scaled via Q) ----
    f32x4 s[2][4];
#pragma unroll
    for (int m = 0; m < 2; ++m)
#pragma unroll
      for (int n = 0; n < 4; ++n) s[m][n] = z4;
    __builtin_amdgcn_s_setprio(1);
#pragma unroll
    for (int kq = 0; kq < 2; ++kq)
#pragma unroll
      for (int m = 0; m < 2; ++m)
#pragma unroll
        for (int n = 0; n < 4; ++n)
          s[m][n] = __builtin_amdgcn_mfma_f32_16x16x32_bf16(qf[m][kq], ka[kq][n], s[m][n], 0, 0, 0);
#pragma unroll
    for (int kq = 0; kq < 2; ++kq)
#pragma unroll
      for (int m = 0; m < 2; ++m)
#pragma unroll
        for (int n = 0; n < 4; ++n)
          s[m][n] = __builtin_amdgcn_mfma_f32_16x16x32_bf16(qf[m][kq + 2], kb[kq][n], s[m][n], 0, 0, 0);
    __builtin_amdgcn_s_setprio(0);

    // ---- issue V loads; consumed after softmax (latency hidden) ----
    bf16x8 vreg[2][8]; // [kk][dn]
#pragma unroll
    for (int kk = 0; kk < 2; ++kk)
#pragma unroll
      for (int dn = 0; dn < 8; ++dn)
        vreg[kk][dn] = *(const bf16x8*)(vth + (size_t)(dn * 16 + rowA) * 2048 + kv0 + kk * 32 + kgrp);

    // ---- prefetch next tile's first K half (covered by softmax+PV) ----
    if (it + 1 < nt) {
#pragma unroll
      for (int kq = 0; kq < 2; ++kq)
#pragma unroll
        for (int n = 0; n < 4; ++n)
          ka[kq][n] = *(const bf16x8*)(kh + (size_t)(kv0 + 64 + n * 16 + rowA) * 128 + kq * 32 + kgrp);
    }

    // ---- causal mask: wave-uniform branch, last tile only ----
    if (it == nt - 1) {
#pragma unroll
      for (int m = 0; m < 2; ++m)
#pragma unroll
        for (int n = 0; n < 4; ++n)
#pragma unroll
          for (int r = 0; r < 4; ++r) {
            int qg = q0 + m * 16 + rgrp + r;
            int kg = kv0 + n * 16 + rowA;
            if (kg > qg) s[m][n][r] = -1e30f;
          }
    }

    // ---- online softmax (base-2), step-major shfl trees, defer-max (T13) ----
    float tmax[2][4];
#pragma unroll
    for (int m = 0; m < 2; ++m)
#pragma unroll
      for (int r = 0; r < 4; ++r)
        tmax[m][r] = fmaxf(fmaxf(s[m][0][r], s[m][1][r]), fmaxf(s[m][2][r], s[m][3][r]));
#pragma unroll
    for (int stp = 1; stp <= 8; stp <<= 1)
#pragma unroll
      for (int m = 0; m < 2; ++m)
#pragma unroll
        for (int r = 0; r < 4; ++r)
          tmax[m][r] = fmaxf(tmax[m][r], __shfl_xor(tmax[m][r], stp));

    bool ok = true;
#pragma unroll
    for (int m = 0; m < 2; ++m)
#pragma unroll
      for (int r = 0; r < 4; ++r) ok = ok && (tmax[m][r] <= mprev[m][r] + 8.0f);
    const bool skip = __all(ok ? 1 : 0);

    float mnew[2][4], psum[2][4];
#pragma unroll
    for (int m = 0; m < 2; ++m)
#pragma unroll
      for (int r = 0; r < 4; ++r) {
        mnew[m][r] = skip ? mprev[m][r] : fmaxf(mprev[m][r], tmax[m][r]);
        float ps = 0.f;
#pragma unroll
        for (int n = 0; n < 4; ++n) {
          float p = exp2f(s[m][n][r] - mnew[m][r]);
          s[m][n][r] = p;
          ps += p;
        }
        psum[m][r] = ps;
      }
#pragma unroll
    for (int stp = 1; stp <= 8; stp <<= 1)
#pragma unroll
      for (int m = 0; m < 2; ++m)
#pragma unroll
        for (int r = 0; r < 4; ++r)
          psum[m][r] += __shfl_xor(psum[m][r], stp);

#pragma unroll
    for (int m = 0; m < 2; ++m)
#pragma unroll
      for (int r = 0; r < 4; ++r) {
        if (skip) {
          lsum[m][r] += psum[m][r];
        } else {
          float alpha = exp2f(mprev[m][r] - mnew[m][r]);
          lsum[m][r] = lsum[m][r] * alpha + psum[m][r];
          mprev[m][r] = mnew[m][r];
#pragma unroll
          for (int dn = 0; dn < 8; ++dn) o[m][dn][r] *= alpha;
        }
      }

    // ---- P: C/D-frag layout -> A-operand layout via swizzled LDS ----
#pragma unroll
    for (int m = 0; m < 2; ++m)
#pragma unroll
      for (int n = 0; n < 4; ++n)
#pragma unroll
        for (int r = 0; r < 4; ++r) {
          int row = m * 16 + rgrp + r;
          int col = n * 16 + rowA;
          Plds[row * 64 + (col ^ ((row & 7) << 3))] = f2bf(s[m][n][r]);
        }
    // single wave: DS ops retire in order; compiler inserts lgkmcnt waits

    bf16x8 pa[2][2];
#pragma unroll
    for (int m = 0; m < 2; ++m)
#pragma unroll
      for (int kk = 0; kk < 2; ++kk) {
        int row = m * 16 + rowA;
        int col0 = kk * 32 + kgrp;
        pa[m][kk] = *(const bf16x8*)&Plds[row * 64 + (col0 ^ ((row & 7) << 3))];
      }

    // ---- O += P @ V (V already in registers) ----
    __builtin_amdgcn_s_setprio(1);
#pragma unroll
    for (int kk = 0; kk < 2; ++kk)
#pragma unroll
      for (int dn = 0; dn < 8; ++dn)
#pragma unroll
        for (int m = 0; m < 2; ++m)
          o[m][dn] = __builtin_amdgcn_mfma_f32_16x16x32_bf16(pa[m][kk], vreg[kk][dn], o[m][dn], 0, 0, 0);
    __builtin_amdgcn_s_setprio(0);
  }

  // epilogue: normalize (one reciprocal per row) and write bf16 [B,T,C]
  float rinv[2][4];
#pragma unroll
  for (int m = 0; m < 2; ++m)
#pragma unroll
    for (int r = 0; r < 4; ++r) rinv[m][r] = 1.0f / lsum[m][r];
#pragma unroll
  for (int m = 0; m < 2; ++m)
#pragma unroll
    for (int dn = 0; dn < 8; ++dn)
#pragma unroll
      for (int r = 0; r < 4; ++r) {
        float v = o[m][dn][r] * rinv[m][r];
        int t = q0 + m * 16 + rgrp + r;
        int col = h * 128 + dn * 16 + rowA;
        obt[((size_t)b * 2048 + t) * 2048 + col] = f2bf(v);
      }
}

// ---- host launch -----------------------------------------------------------
extern "C" void kernel_launch(void* const* d_in, const int* in_sizes, int n_in,
                              void* d_out, int out_size, void* d_ws, size_t ws_size,
                              hipStream_t stream) {
  const float* x  = (const float*)d_in[0];
  const float* Wq = (const float*)d_in[2];
  const float* Wk = (const float*)d_in[3];
  const float* Wv = (const float*)d_in[4];
  const float* Wo = (const float*)d_in[5];
  float* out = (float*)d_out;

  char* ws = (char*)d_ws;
  unsigned short* xb  = (unsigned short*)(ws + 0);
  unsigned short* wqb = (unsigned short*)(ws + 16777216);
  unsigned short* wkb = (unsigned short*)(ws + 25165824);
  unsigned short* wvb = (unsigned short*)(ws + 33554432);
  unsigned short* wob = (unsigned short*)(ws + 41943040);
  unsigned short* qb  = (unsigned short*)(ws + 50331648);
  unsigned short* kb  = (unsigned short*)(ws + 67108864);
  unsigned short* vtb = (unsigned short*)(ws + 83886080);
  unsigned short* obt = (unsigned short*)(ws + 100663296);
  float* ct = (float*)(ws + 117440512);
  float* st = (float*)(ws + 117964800);

  k_cvt5<<<2048, 256, 0, stream>>>(x, Wq, Wk, Wv, Wo, xb, wqb, wkb, wvb, wob);
  k_rope_tables<<<512, 256, 0, stream>>>(ct, st);
  dim3 gg(16, 32);
  k_gemm<1><<<gg, 256, 0, stream>>>(xb, wqb, (void*)qb,  4096, 2048, 2048);
  k_gemm<1><<<gg, 256, 0, stream>>>(xb, wkb, (void*)kb,  4096, 2048, 2048);
  k_gemm<2><<<gg, 256, 0, stream>>>(xb, wvb, (void*)vtb, 4096, 2048, 2048);
  k_rope<<<16384, 256, 0, stream>>>(qb, kb, ct, st);
  k_flash<<<2048, 64, 0, stream>>>(qb, kb, vtb, obt);
  k_gemm<0><<<gg, 256, 0, stream>>>(obt, wob, (void*)out, 4096, 2048, 2048);
}

// Round 7
// 378.731 us; speedup vs baseline: 3.2949x; 3.2949x over previous
//
#include <hip/hip_runtime.h>
#include <stdint.h>

#define AS1 __attribute__((address_space(1)))
#define AS3 __attribute__((address_space(3)))

using bf16x8 = __attribute__((ext_vector_type(8))) short;
using f32x4  = __attribute__((ext_vector_type(4))) float;

// ---- helpers -------------------------------------------------------------
__device__ __forceinline__ unsigned short f2bf(float f) {
  union { float f; unsigned u; } v; v.f = f;
  return (unsigned short)((v.u + 0x7FFFu + ((v.u >> 16) & 1u)) >> 16); // RNE
}
__device__ __forceinline__ float bf2f(unsigned short h) {
  union { unsigned u; float f; } v; v.u = ((unsigned)h) << 16;
  return v.f;
}
// async global->LDS, 16B per lane; lds dest must be wave-uniform base (HW adds lane*16)
__device__ __forceinline__ void gload_lds16(const void* g, void* l) {
  __builtin_amdgcn_global_load_lds((AS1 const void*)g, (AS3 void*)l, 16, 0, 0);
}

// ---- fused fp32 -> bf16 convert for x + 4 weights (one launch) ------------
// totals: x = 2,097,152 float4; each weight = 1,048,576 float4; sum = 6,291,456
__global__ void k_cvt5(const float* __restrict__ x,  const float* __restrict__ wq,
                       const float* __restrict__ wk, const float* __restrict__ wv,
                       const float* __restrict__ wo,
                       unsigned short* __restrict__ xb,  unsigned short* __restrict__ wqb,
                       unsigned short* __restrict__ wkb, unsigned short* __restrict__ wvb,
                       unsigned short* __restrict__ wob) {
  int idx = blockIdx.x * blockDim.x + threadIdx.x;
  int stride = gridDim.x * blockDim.x;
  for (int i = idx; i < 6291456; i += stride) {
    const float* src; unsigned short* dst; int off;
    if (i < 2097152) { src = x; dst = xb; off = i; }
    else {
      int j = i - 2097152;
      int w = j >> 20;            // 1,048,576 float4 per weight
      off = j & 1048575;
      src = (w == 0) ? wq : (w == 1) ? wk : (w == 2) ? wv : wo;
      dst = (w == 0) ? wqb : (w == 1) ? wkb : (w == 2) ? wvb : wob;
    }
    float4 f = ((const float4*)src)[off];
    ushort4 o;
    o.x = f2bf(f.x); o.y = f2bf(f.y); o.z = f2bf(f.z); o.w = f2bf(f.w);
    ((ushort4*)dst)[off] = o;
  }
}

// ---- RoPE tables: cos/sin[t][i], i in [0,64) ------------------------------
__global__ void k_rope_tables(float* __restrict__ ct, float* __restrict__ st) {
  int idx = blockIdx.x * blockDim.x + threadIdx.x; // T*64 threads
  int t = idx >> 6, i = idx & 63;
  float invf = exp2f(-(float)i * (13.287712379549449f / 64.0f));
  float a = (float)t * invf;
  ct[idx] = cosf(a);
  st[idx] = sinf(a);
}

// ---- RoPE apply in-place on q and k [BH, T, 128] bf16 ---------------------
// q additionally pre-scaled by (1/sqrt(128))*log2(e) so flash logits are
// already base-2 (kills the per-step scale multiply in k_flash).
__global__ void k_rope(unsigned short* __restrict__ q, unsigned short* __restrict__ k,
                       const float* __restrict__ ct, const float* __restrict__ st) {
  const float SC2 = 0.12751659974141322f;
  int idx = blockIdx.x * blockDim.x + threadIdx.x; // B*H*T*64 threads
  int i = idx & 63;
  int t = (idx >> 6) & 2047;
  int bh = idx >> 17;
  size_t base = ((size_t)bh * 2048 + t) * 128;
  float c = ct[t * 64 + i], s = st[t * 64 + i];
  {
    float x1 = bf2f(q[base + i]), x2 = bf2f(q[base + i + 64]);
    q[base + i]      = f2bf((x1 * c - x2 * s) * SC2);
    q[base + i + 64] = f2bf((x2 * c + x1 * s) * SC2);
  }
  {
    float x1 = bf2f(k[base + i]), x2 = bf2f(k[base + i + 64]);
    k[base + i]      = f2bf(x1 * c - x2 * s);
    k[base + i + 64] = f2bf(x2 * c + x1 * s);
  }
}

// ---- GEMM: C = A @ B^T. A:[M,K] bf16 rowmajor, Bw:[N,K] bf16 rowmajor.
// MODE 0: f32 out [M,N]
// MODE 1: bf16 out at [b,h,t,d]  -> Q/K layout
// MODE 2: bf16 out at [b,h,d,t]  -> transposed V layout
template <int MODE>
__global__ __launch_bounds__(256) void k_gemm(const unsigned short* __restrict__ A,
                                              const unsigned short* __restrict__ Bw,
                                              void* __restrict__ Cout,
                                              int M, int N, int K) {
  __shared__ __align__(16) unsigned short As[128 * 64];
  __shared__ __align__(16) unsigned short Bs[128 * 64];

  const int tid = threadIdx.x;
  const int wid = tid >> 6, lane = tid & 63;
  const int wm = wid >> 1, wn = wid & 1;
  const int m0 = blockIdx.y * 128, n0 = blockIdx.x * 128;
  const int rowA = lane & 15;
  const int kgrp = (lane >> 4) * 8;
  const int rgrp = (lane >> 4) * 4;
  const int srow = lane >> 3;
  const int scol = (lane & 7) * 8;

  f32x4 acc[4][4];
  const f32x4 z4 = {0.f, 0.f, 0.f, 0.f};
#pragma unroll
  for (int i = 0; i < 4; ++i)
#pragma unroll
    for (int j = 0; j < 4; ++j) acc[i][j] = z4;

  for (int k0 = 0; k0 < K; k0 += 64) {
    __syncthreads();
#pragma unroll
    for (int i = 0; i < 4; ++i) {
      int c = wid * 4 + i;
      const unsigned short* ga = A  + (size_t)(m0 + c * 8 + srow) * K + k0 + scol;
      gload_lds16(ga, (void*)&As[c * 512]);
      const unsigned short* gb = Bw + (size_t)(n0 + c * 8 + srow) * K + k0 + scol;
      gload_lds16(gb, (void*)&Bs[c * 512]);
    }
    __syncthreads();
#pragma unroll
    for (int kk = 0; kk < 64; kk += 32) {
      bf16x8 af[4], bfv[4];
#pragma unroll
      for (int i = 0; i < 4; ++i)
        af[i] = *(const bf16x8*)&As[(wm * 64 + i * 16 + rowA) * 64 + kk + kgrp];
#pragma unroll
      for (int j = 0; j < 4; ++j)
        bfv[j] = *(const bf16x8*)&Bs[(wn * 64 + j * 16 + rowA) * 64 + kk + kgrp];
#pragma unroll
      for (int i = 0; i < 4; ++i)
#pragma unroll
        for (int j = 0; j < 4; ++j)
          acc[i][j] = __builtin_amdgcn_mfma_f32_16x16x32_bf16(af[i], bfv[j], acc[i][j], 0, 0, 0);
    }
  }

#pragma unroll
  for (int i = 0; i < 4; ++i) {
#pragma unroll
    for (int j = 0; j < 4; ++j) {
      if (MODE == 2) {
        int gn = n0 + wn * 64 + j * 16 + rowA;
        int h = gn >> 7, d = gn & 127;
        int gmb = m0 + wm * 64 + i * 16 + rgrp;
        int b = gmb >> 11, t = gmb & 2047;
        ushort4 pk;
        pk.x = f2bf(acc[i][j][0]); pk.y = f2bf(acc[i][j][1]);
        pk.z = f2bf(acc[i][j][2]); pk.w = f2bf(acc[i][j][3]);
        *(ushort4*)&((unsigned short*)Cout)[(((size_t)(b * 16 + h)) * 128 + d) * 2048 + t] = pk;
      } else {
#pragma unroll
        for (int r = 0; r < 4; ++r) {
          int gm = m0 + wm * 64 + i * 16 + rgrp + r;
          int gn = n0 + wn * 64 + j * 16 + rowA;
          float v = acc[i][j][r];
          if (MODE == 0) {
            ((float*)Cout)[(size_t)gm * N + gn] = v;
          } else {
            int b = gm >> 11, t = gm & 2047;
            int h = gn >> 7, d = gn & 127;
            ((unsigned short*)Cout)[(((size_t)(b * 16 + h)) * 2048 + t) * 128 + d] = f2bf(v);
          }
        }
      }
    }
  }
}

// ---- flash attention fwd: ONE WAVE per block, 32 q rows, 64-wide KV tiles
// Pipelined: K loaded in halves (next tile's first half prefetched during PV),
// V issued post-QK and consumed post-softmax, causal mask hoisted to last tile,
// Q pre-scaled at RoPE (logits already base-2). K/V L2-resident (4 heads/XCD).
// __launch_bounds__(64) is REQUIRED: without it the compiler allocates for
// 1024-thread worst case -> caps at 64 VGPR -> 1.5GB of scratch spills (r6).
__global__ __launch_bounds__(64) void k_flash(const unsigned short* __restrict__ q,
                                              const unsigned short* __restrict__ k,
                                              const unsigned short* __restrict__ vt,
                                              unsigned short* __restrict__ obt) {
  __shared__ __align__(16) unsigned short Plds[32 * 64]; // 4KB, XOR-swizzled

  const int lane = threadIdx.x;
  const int rowA = lane & 15, kgrp = (lane >> 4) * 8, rgrp = (lane >> 4) * 4;
  const int bid = blockIdx.x;
  const int xcd = bid & 7;            // round-robin XCD dispatch assumption (perf-only)
  const int r0  = bid >> 3;
  const int bh  = xcd * 4 + (r0 & 3); // 4 heads per XCD: K+V = 4MB = one L2
  const int j   = 63 - (r0 >> 2);     // heavy q-tiles dispatch first
  const int q0  = j * 32;
  const int b = bh >> 4, h = bh & 15;

  const unsigned short* qh  = q  + (size_t)bh * 2048 * 128;
  const unsigned short* kh  = k  + (size_t)bh * 2048 * 128;
  const unsigned short* vth = vt + (size_t)bh * 128 * 2048;

  bf16x8 qf[2][4];
#pragma unroll
  for (int m = 0; m < 2; ++m)
#pragma unroll
    for (int kq = 0; kq < 4; ++kq)
      qf[m][kq] = *(const bf16x8*)(qh + (size_t)(q0 + m * 16 + rowA) * 128 + kq * 32 + kgrp);

  const f32x4 z4 = {0.f, 0.f, 0.f, 0.f};
  f32x4 o[2][8];
  float mprev[2][4], lsum[2][4];
#pragma unroll
  for (int m = 0; m < 2; ++m) {
#pragma unroll
    for (int dn = 0; dn < 8; ++dn) o[m][dn] = z4;
#pragma unroll
    for (int r = 0; r < 4; ++r) { mprev[m][r] = -1e30f; lsum[m][r] = 0.f; }
  }

  const int nt = (q0 >> 6) + 1; // 64-wide tiles; only last needs mask

  // K fragments in halves: ka = kq 0..1, kb = kq 2..3 (each 8 frags, 32 VGPR)
  bf16x8 ka[2][4], kb[2][4];
#pragma unroll
  for (int kq = 0; kq < 2; ++kq)
#pragma unroll
    for (int n = 0; n < 4; ++n)
      ka[kq][n] = *(const bf16x8*)(kh + (size_t)(n * 16 + rowA) * 128 + kq * 32 + kgrp);

  for (int it = 0; it < nt; ++it) {
    const int kv0 = it * 64;

    // second K half for this tile (covered by first-half QK below)
#pragma unroll
    for (int kq = 0; kq < 2; ++kq)
#pragma unroll
      for (int n = 0; n < 4; ++n)
        kb[kq][n] = *(const bf16x8*)(kh + (size_t)(kv0 + n * 16 + rowA) * 128 + (kq + 2) * 32 + kgrp);

    // ---- S = Q K^T (logits already base-2-scaled via Q) ----
    f32x4 s[2][4];
#pragma unroll
    for (int m = 0; m < 2; ++m)
#pragma unroll
      for (int n = 0; n < 4; ++n) s[m][n] = z4;
    __builtin_amdgcn_s_setprio(1);
#pragma unroll
    for (int kq = 0; kq < 2; ++kq)
#pragma unroll
      for (int m = 0; m < 2; ++m)
#pragma unroll
        for (int n = 0; n < 4; ++n)
          s[m][n] = __builtin_amdgcn_mfma_f32_16x16x32_bf16(qf[m][kq], ka[kq][n], s[m][n], 0, 0, 0);
#pragma unroll
    for (int kq = 0; kq < 2; ++kq)
#pragma unroll
      for (int m = 0; m < 2; ++m)
#pragma unroll
        for (int n = 0; n < 4; ++n)
          s[m][n] = __builtin_amdgcn_mfma_f32_16x16x32_bf16(qf[m][kq + 2], kb[kq][n], s[m][n], 0, 0, 0);
    __builtin_amdgcn_s_setprio(0);

    // ---- issue V loads; consumed after softmax (latency hidden) ----
    bf16x8 vreg[2][8]; // [kk][dn]
#pragma unroll
    for (int kk = 0; kk < 2; ++kk)
#pragma unroll
      for (int dn = 0; dn < 8; ++dn)
        vreg[kk][dn] = *(const bf16x8*)(vth + (size_t)(dn * 16 + rowA) * 2048 + kv0 + kk * 32 + kgrp);

    // ---- prefetch next tile's first K half (covered by softmax+PV) ----
    if (it + 1 < nt) {
#pragma unroll
      for (int kq = 0; kq < 2; ++kq)
#pragma unroll
        for (int n = 0; n < 4; ++n)
          ka[kq][n] = *(const bf16x8*)(kh + (size_t)(kv0 + 64 + n * 16 + rowA) * 128 + kq * 32 + kgrp);
    }

    // ---- causal mask: wave-uniform branch, last tile only ----
    if (it == nt - 1) {
#pragma unroll
      for (int m = 0; m < 2; ++m)
#pragma unroll
        for (int n = 0; n < 4; ++n)
#pragma unroll
          for (int r = 0; r < 4; ++r) {
            int qg = q0 + m * 16 + rgrp + r;
            int kg = kv0 + n * 16 + rowA;
            if (kg > qg) s[m][n][r] = -1e30f;
          }
    }

    // ---- online softmax (base-2), step-major shfl trees, defer-max (T13) ----
    float tmax[2][4];
#pragma unroll
    for (int m = 0; m < 2; ++m)
#pragma unroll
      for (int r = 0; r < 4; ++r)
        tmax[m][r] = fmaxf(fmaxf(s[m][0][r], s[m][1][r]), fmaxf(s[m][2][r], s[m][3][r]));
#pragma unroll
    for (int stp = 1; stp <= 8; stp <<= 1)
#pragma unroll
      for (int m = 0; m < 2; ++m)
#pragma unroll
        for (int r = 0; r < 4; ++r)
          tmax[m][r] = fmaxf(tmax[m][r], __shfl_xor(tmax[m][r], stp));

    bool ok = true;
#pragma unroll
    for (int m = 0; m < 2; ++m)
#pragma unroll
      for (int r = 0; r < 4; ++r) ok = ok && (tmax[m][r] <= mprev[m][r] + 8.0f);
    const bool skip = __all(ok ? 1 : 0);

    float mnew[2][4], psum[2][4];
#pragma unroll
    for (int m = 0; m < 2; ++m)
#pragma unroll
      for (int r = 0; r < 4; ++r) {
        mnew[m][r] = skip ? mprev[m][r] : fmaxf(mprev[m][r], tmax[m][r]);
        float ps = 0.f;
#pragma unroll
        for (int n = 0; n < 4; ++n) {
          float p = exp2f(s[m][n][r] - mnew[m][r]);
          s[m][n][r] = p;
          ps += p;
        }
        psum[m][r] = ps;
      }
#pragma unroll
    for (int stp = 1; stp <= 8; stp <<= 1)
#pragma unroll
      for (int m = 0; m < 2; ++m)
#pragma unroll
        for (int r = 0; r < 4; ++r)
          psum[m][r] += __shfl_xor(psum[m][r], stp);

#pragma unroll
    for (int m = 0; m < 2; ++m)
#pragma unroll
      for (int r = 0; r < 4; ++r) {
        if (skip) {
          lsum[m][r] += psum[m][r];
        } else {
          float alpha = exp2f(mprev[m][r] - mnew[m][r]);
          lsum[m][r] = lsum[m][r] * alpha + psum[m][r];
          mprev[m][r] = mnew[m][r];
#pragma unroll
          for (int dn = 0; dn < 8; ++dn) o[m][dn][r] *= alpha;
        }
      }

    // ---- P: C/D-frag layout -> A-operand layout via swizzled LDS ----
#pragma unroll
    for (int m = 0; m < 2; ++m)
#pragma unroll
      for (int n = 0; n < 4; ++n)
#pragma unroll
        for (int r = 0; r < 4; ++r) {
          int row = m * 16 + rgrp + r;
          int col = n * 16 + rowA;
          Plds[row * 64 + (col ^ ((row & 7) << 3))] = f2bf(s[m][n][r]);
        }
    // single wave: DS ops retire in order; compiler inserts lgkmcnt waits

    bf16x8 pa[2][2];
#pragma unroll
    for (int m = 0; m < 2; ++m)
#pragma unroll
      for (int kk = 0; kk < 2; ++kk) {
        int row = m * 16 + rowA;
        int col0 = kk * 32 + kgrp;
        pa[m][kk] = *(const bf16x8*)&Plds[row * 64 + (col0 ^ ((row & 7) << 3))];
      }

    // ---- O += P @ V (V already in registers) ----
    __builtin_amdgcn_s_setprio(1);
#pragma unroll
    for (int kk = 0; kk < 2; ++kk)
#pragma unroll
      for (int dn = 0; dn < 8; ++dn)
#pragma unroll
        for (int m = 0; m < 2; ++m)
          o[m][dn] = __builtin_amdgcn_mfma_f32_16x16x32_bf16(pa[m][kk], vreg[kk][dn], o[m][dn], 0, 0, 0);
    __builtin_amdgcn_s_setprio(0);
  }

  // epilogue: normalize (one reciprocal per row) and write bf16 [B,T,C]
  float rinv[2][4];
#pragma unroll
  for (int m = 0; m < 2; ++m)
#pragma unroll
    for (int r = 0; r < 4; ++r) rinv[m][r] = 1.0f / lsum[m][r];
#pragma unroll
  for (int m = 0; m < 2; ++m)
#pragma unroll
    for (int dn = 0; dn < 8; ++dn)
#pragma unroll
      for (int r = 0; r < 4; ++r) {
        float v = o[m][dn][r] * rinv[m][r];
        int t = q0 + m * 16 + rgrp + r;
        int col = h * 128 + dn * 16 + rowA;
        obt[((size_t)b * 2048 + t) * 2048 + col] = f2bf(v);
      }
}

// ---- host launch -----------------------------------------------------------
extern "C" void kernel_launch(void* const* d_in, const int* in_sizes, int n_in,
                              void* d_out, int out_size, void* d_ws, size_t ws_size,
                              hipStream_t stream) {
  const float* x  = (const float*)d_in[0];
  const float* Wq = (const float*)d_in[2];
  const float* Wk = (const float*)d_in[3];
  const float* Wv = (const float*)d_in[4];
  const float* Wo = (const float*)d_in[5];
  float* out = (float*)d_out;

  char* ws = (char*)d_ws;
  unsigned short* xb  = (unsigned short*)(ws + 0);
  unsigned short* wqb = (unsigned short*)(ws + 16777216);
  unsigned short* wkb = (unsigned short*)(ws + 25165824);
  unsigned short* wvb = (unsigned short*)(ws + 33554432);
  unsigned short* wob = (unsigned short*)(ws + 41943040);
  unsigned short* qb  = (unsigned short*)(ws + 50331648);
  unsigned short* kb  = (unsigned short*)(ws + 67108864);
  unsigned short* vtb = (unsigned short*)(ws + 83886080);
  unsigned short* obt = (unsigned short*)(ws + 100663296);
  float* ct = (float*)(ws + 117440512);
  float* st = (float*)(ws + 117964800);

  k_cvt5<<<2048, 256, 0, stream>>>(x, Wq, Wk, Wv, Wo, xb, wqb, wkb, wvb, wob);
  k_rope_tables<<<512, 256, 0, stream>>>(ct, st);
  dim3 gg(16, 32);
  k_gemm<1><<<gg, 256, 0, stream>>>(xb, wqb, (void*)qb,  4096, 2048, 2048);
  k_gemm<1><<<gg, 256, 0, stream>>>(xb, wkb, (void*)kb,  4096, 2048, 2048);
  k_gemm<2><<<gg, 256, 0, stream>>>(xb, wvb, (void*)vtb, 4096, 2048, 2048);
  k_rope<<<16384, 256, 0, stream>>>(qb, kb, ct, st);
  k_flash<<<2048, 64, 0, stream>>>(qb, kb, vtb, obt);
  k_gemm<0><<<gg, 256, 0, stream>>>(obt, wob, (void*)out, 4096, 2048, 2048);
}

// Round 8
// 356.053 us; speedup vs baseline: 3.5047x; 1.0637x over previous
//
#include <hip/hip_runtime.h>
#include <stdint.h>

#define AS1 __attribute__((address_space(1)))
#define AS3 __attribute__((address_space(3)))

using bf16x8 = __attribute__((ext_vector_type(8))) short;
using f32x4  = __attribute__((ext_vector_type(4))) float;

// ---- helpers -------------------------------------------------------------
__device__ __forceinline__ unsigned short f2bf(float f) {
  union { float f; unsigned u; } v; v.f = f;
  return (unsigned short)((v.u + 0x7FFFu + ((v.u >> 16) & 1u)) >> 16); // RNE
}
__device__ __forceinline__ float bf2f(unsigned short h) {
  union { unsigned u; float f; } v; v.u = ((unsigned)h) << 16;
  return v.f;
}
// async global->LDS, 16B per lane; lds dest must be wave-uniform base (HW adds lane*16)
__device__ __forceinline__ void gload_lds16(const void* g, void* l) {
  __builtin_amdgcn_global_load_lds((AS1 const void*)g, (AS3 void*)l, 16, 0, 0);
}

// ---- fused fp32 -> bf16 convert for x + 4 weights (one launch) ------------
// totals: x = 2,097,152 float4; each weight = 1,048,576 float4; sum = 6,291,456
__global__ void k_cvt5(const float* __restrict__ x,  const float* __restrict__ wq,
                       const float* __restrict__ wk, const float* __restrict__ wv,
                       const float* __restrict__ wo,
                       unsigned short* __restrict__ xb,  unsigned short* __restrict__ wqb,
                       unsigned short* __restrict__ wkb, unsigned short* __restrict__ wvb,
                       unsigned short* __restrict__ wob) {
  int idx = blockIdx.x * blockDim.x + threadIdx.x;
  int stride = gridDim.x * blockDim.x;
  for (int i = idx; i < 6291456; i += stride) {
    const float* src; unsigned short* dst; int off;
    if (i < 2097152) { src = x; dst = xb; off = i; }
    else {
      int j = i - 2097152;
      int w = j >> 20;            // 1,048,576 float4 per weight
      off = j & 1048575;
      src = (w == 0) ? wq : (w == 1) ? wk : (w == 2) ? wv : wo;
      dst = (w == 0) ? wqb : (w == 1) ? wkb : (w == 2) ? wvb : wob;
    }
    float4 f = ((const float4*)src)[off];
    ushort4 o;
    o.x = f2bf(f.x); o.y = f2bf(f.y); o.z = f2bf(f.z); o.w = f2bf(f.w);
    ((ushort4*)dst)[off] = o;
  }
}

// ---- RoPE tables: cos/sin[t][i], i in [0,64) ------------------------------
__global__ void k_rope_tables(float* __restrict__ ct, float* __restrict__ st) {
  int idx = blockIdx.x * blockDim.x + threadIdx.x; // T*64 threads
  int t = idx >> 6, i = idx & 63;
  float invf = exp2f(-(float)i * (13.287712379549449f / 64.0f));
  float a = (float)t * invf;
  ct[idx] = cosf(a);
  st[idx] = sinf(a);
}

// ---- RoPE apply in-place on q and k [BH, T, 128] bf16 ---------------------
// q additionally pre-scaled by (1/sqrt(128))*log2(e): flash logits are base-2.
__global__ void k_rope(unsigned short* __restrict__ q, unsigned short* __restrict__ k,
                       const float* __restrict__ ct, const float* __restrict__ st) {
  const float SC2 = 0.12751659974141322f;
  int idx = blockIdx.x * blockDim.x + threadIdx.x; // B*H*T*64 threads
  int i = idx & 63;
  int t = (idx >> 6) & 2047;
  int bh = idx >> 17;
  size_t base = ((size_t)bh * 2048 + t) * 128;
  float c = ct[t * 64 + i], s = st[t * 64 + i];
  {
    float x1 = bf2f(q[base + i]), x2 = bf2f(q[base + i + 64]);
    q[base + i]      = f2bf((x1 * c - x2 * s) * SC2);
    q[base + i + 64] = f2bf((x2 * c + x1 * s) * SC2);
  }
  {
    float x1 = bf2f(k[base + i]), x2 = bf2f(k[base + i + 64]);
    k[base + i]      = f2bf(x1 * c - x2 * s);
    k[base + i + 64] = f2bf(x2 * c + x1 * s);
  }
}

// ---- GEMM: C = A @ B^T. A:[M,K] bf16 rowmajor, Bw:[N,K] bf16 rowmajor.
// MODE 0: f32 out [M,N]
// MODE 1: bf16 out at [b,h,t,d]  -> Q/K layout
// MODE 2: bf16 out at [b,h,d,t]  -> transposed V layout
template <int MODE>
__global__ __launch_bounds__(256) void k_gemm(const unsigned short* __restrict__ A,
                                              const unsigned short* __restrict__ Bw,
                                              void* __restrict__ Cout,
                                              int M, int N, int K) {
  __shared__ __align__(16) unsigned short As[128 * 64];
  __shared__ __align__(16) unsigned short Bs[128 * 64];

  const int tid = threadIdx.x;
  const int wid = tid >> 6, lane = tid & 63;
  const int wm = wid >> 1, wn = wid & 1;
  const int m0 = blockIdx.y * 128, n0 = blockIdx.x * 128;
  const int rowA = lane & 15;
  const int kgrp = (lane >> 4) * 8;
  const int rgrp = (lane >> 4) * 4;
  const int srow = lane >> 3;
  const int scol = (lane & 7) * 8;

  f32x4 acc[4][4];
  const f32x4 z4 = {0.f, 0.f, 0.f, 0.f};
#pragma unroll
  for (int i = 0; i < 4; ++i)
#pragma unroll
    for (int j = 0; j < 4; ++j) acc[i][j] = z4;

  for (int k0 = 0; k0 < K; k0 += 64) {
    __syncthreads();
#pragma unroll
    for (int i = 0; i < 4; ++i) {
      int c = wid * 4 + i;
      const unsigned short* ga = A  + (size_t)(m0 + c * 8 + srow) * K + k0 + scol;
      gload_lds16(ga, (void*)&As[c * 512]);
      const unsigned short* gb = Bw + (size_t)(n0 + c * 8 + srow) * K + k0 + scol;
      gload_lds16(gb, (void*)&Bs[c * 512]);
    }
    __syncthreads();
#pragma unroll
    for (int kk = 0; kk < 64; kk += 32) {
      bf16x8 af[4], bfv[4];
#pragma unroll
      for (int i = 0; i < 4; ++i)
        af[i] = *(const bf16x8*)&As[(wm * 64 + i * 16 + rowA) * 64 + kk + kgrp];
#pragma unroll
      for (int j = 0; j < 4; ++j)
        bfv[j] = *(const bf16x8*)&Bs[(wn * 64 + j * 16 + rowA) * 64 + kk + kgrp];
#pragma unroll
      for (int i = 0; i < 4; ++i)
#pragma unroll
        for (int j = 0; j < 4; ++j)
          acc[i][j] = __builtin_amdgcn_mfma_f32_16x16x32_bf16(af[i], bfv[j], acc[i][j], 0, 0, 0);
    }
  }

#pragma unroll
  for (int i = 0; i < 4; ++i) {
#pragma unroll
    for (int j = 0; j < 4; ++j) {
      if (MODE == 2) {
        int gn = n0 + wn * 64 + j * 16 + rowA;
        int h = gn >> 7, d = gn & 127;
        int gmb = m0 + wm * 64 + i * 16 + rgrp;
        int b = gmb >> 11, t = gmb & 2047;
        ushort4 pk;
        pk.x = f2bf(acc[i][j][0]); pk.y = f2bf(acc[i][j][1]);
        pk.z = f2bf(acc[i][j][2]); pk.w = f2bf(acc[i][j][3]);
        *(ushort4*)&((unsigned short*)Cout)[(((size_t)(b * 16 + h)) * 128 + d) * 2048 + t] = pk;
      } else {
#pragma unroll
        for (int r = 0; r < 4; ++r) {
          int gm = m0 + wm * 64 + i * 16 + rgrp + r;
          int gn = n0 + wn * 64 + j * 16 + rowA;
          float v = acc[i][j][r];
          if (MODE == 0) {
            ((float*)Cout)[(size_t)gm * N + gn] = v;
          } else {
            int b = gm >> 11, t = gm & 2047;
            int h = gn >> 7, d = gn & 127;
            ((unsigned short*)Cout)[(((size_t)(b * 16 + h)) * 2048 + t) * 128 + d] = f2bf(v);
          }
        }
      }
    }
  }
}

// ---- flash attention fwd: 4 waves/block share LDS-staged K/V --------------
// Block = 256 thr, QBLK=128 (wave wid owns rows Q0+wid*32..+32). K[64][128] and
// V[128][64] double-buffered in LDS via global_load_lds with PRE-SWIZZLED
// GLOBAL source (chunk ^= row&7 on 16B chunks; LDS dest linear — rule 21),
// read back with the same XOR -> <=2-way bank conflicts (free). L2 K/V
// traffic /4 vs 1-wave blocks. One barrier per tile (stage t+1 || compute t).
__global__ __launch_bounds__(256) void k_flash(const unsigned short* __restrict__ q,
                                               const unsigned short* __restrict__ k,
                                               const unsigned short* __restrict__ vt,
                                               unsigned short* __restrict__ obt) {
  // 80KB: K dbuf 2x8192 ush | V dbuf 2x8192 ush @16384 | P 4x2048 ush @32768
  __shared__ __align__(16) unsigned short lds[40960];

  const int tid = threadIdx.x;
  const int wid = tid >> 6, lane = tid & 63;
  const int rowA = lane & 15, kg = lane >> 4;
  const int kgrp = kg * 8, rgrp = kg * 4;

  const int bid = blockIdx.x;
  const int xcd = bid & 7;            // round-robin XCD dispatch assumption (perf-only)
  const int r0  = bid >> 3;           // 0..63
  const int bh  = xcd * 4 + (r0 & 3); // 4 heads per XCD chunk
  const int jb  = 15 - (r0 >> 2);     // heavy q-tiles dispatch first
  const int Q0  = jb * 128;
  const int q0w = Q0 + wid * 32;
  const int b = bh >> 4, h = bh & 15;

  const unsigned short* qh  = q  + (size_t)bh * 2048 * 128;
  const unsigned short* kh  = k  + (size_t)bh * 2048 * 128;
  const unsigned short* vth = vt + (size_t)bh * 128 * 2048;

  // staging lane constants
  const int kRow0 = wid * 16 + (lane >> 4); // + i*4 -> K tile row (kv)
  const int vRow0 = wid * 32 + (lane >> 3); // + i*8 -> V tile row (d)
  const int vCh   = (lane & 7) ^ ((lane >> 3) & 7); // V: row&7 == (lane>>3)&7

  // stage one K/V tile into buffer `buf` (per wave: 4+4 gload_lds calls)
  auto STAGE = [&](int buf, int kt) {
    const int kv0 = kt * 64;
#pragma unroll
    for (int i = 0; i < 4; ++i) {
      int row = kRow0 + i * 4;
      int ch  = (lane & 15) ^ (row & 7);
      gload_lds16(kh + (size_t)(kv0 + row) * 128 + ch * 8,
                  (void*)&lds[buf * 8192 + wid * 2048 + i * 512]);
    }
#pragma unroll
    for (int i = 0; i < 4; ++i) {
      int row = vRow0 + i * 8;
      gload_lds16(vth + (size_t)row * 2048 + kv0 + vCh * 8,
                  (void*)&lds[16384 + buf * 8192 + wid * 2048 + i * 512]);
    }
  };

  // Q fragments (pre-scaled at RoPE: logits base-2)
  bf16x8 qf[2][4];
#pragma unroll
  for (int m = 0; m < 2; ++m)
#pragma unroll
    for (int kq = 0; kq < 4; ++kq)
      qf[m][kq] = *(const bf16x8*)(qh + (size_t)(q0w + m * 16 + rowA) * 128 + kq * 32 + kgrp);

  const f32x4 z4 = {0.f, 0.f, 0.f, 0.f};
  f32x4 o[2][8];
  float mprev[2][4], lsum[2][4];
#pragma unroll
  for (int m = 0; m < 2; ++m) {
#pragma unroll
    for (int dn = 0; dn < 8; ++dn) o[m][dn] = z4;
#pragma unroll
    for (int r = 0; r < 4; ++r) { mprev[m][r] = -1e30f; lsum[m][r] = 0.f; }
  }

  const int nt = 2 * jb + 2;
  int cur = 0;
  STAGE(0, 0);
  __syncthreads();

  for (int it = 0; it < nt; ++it) {
    const int kv0 = it * 64;
    if (it + 1 < nt) STAGE(cur ^ 1, it + 1); // async prefetch next tile

    if (kv0 <= q0w + 31) { // skip fully-masked tiles (wave-uniform)
      const unsigned short* Kb = &lds[cur * 8192];
      const unsigned short* Vb = &lds[16384 + cur * 8192];

      // ---- S = Q K^T from swizzled LDS ----
      f32x4 s[2][4];
#pragma unroll
      for (int m = 0; m < 2; ++m)
#pragma unroll
        for (int n = 0; n < 4; ++n) s[m][n] = z4;
      __builtin_amdgcn_s_setprio(1);
#pragma unroll
      for (int kq = 0; kq < 4; ++kq) {
        bf16x8 bk[4];
#pragma unroll
        for (int n = 0; n < 4; ++n) {
          int row = n * 16 + rowA;
          int ch  = (kq * 4 + kg) ^ (row & 7);
          bk[n] = *(const bf16x8*)&Kb[row * 128 + ch * 8];
        }
#pragma unroll
        for (int m = 0; m < 2; ++m)
#pragma unroll
          for (int n = 0; n < 4; ++n)
            s[m][n] = __builtin_amdgcn_mfma_f32_16x16x32_bf16(qf[m][kq], bk[n], s[m][n], 0, 0, 0);
      }
      __builtin_amdgcn_s_setprio(0);

      // ---- causal mask (only tiles overlapping the diagonal) ----
      if (kv0 + 63 > q0w) {
#pragma unroll
        for (int m = 0; m < 2; ++m)
#pragma unroll
          for (int n = 0; n < 4; ++n)
#pragma unroll
            for (int r = 0; r < 4; ++r) {
              int qg = q0w + m * 16 + rgrp + r;
              int kgl = kv0 + n * 16 + rowA;
              if (kgl > qg) s[m][n][r] = -1e30f;
            }
      }

      // ---- online softmax (base-2), step-major shfl trees, defer-max ----
      float tmax[2][4];
#pragma unroll
      for (int m = 0; m < 2; ++m)
#pragma unroll
        for (int r = 0; r < 4; ++r)
          tmax[m][r] = fmaxf(fmaxf(s[m][0][r], s[m][1][r]), fmaxf(s[m][2][r], s[m][3][r]));
#pragma unroll
      for (int stp = 1; stp <= 8; stp <<= 1)
#pragma unroll
        for (int m = 0; m < 2; ++m)
#pragma unroll
          for (int r = 0; r < 4; ++r)
            tmax[m][r] = fmaxf(tmax[m][r], __shfl_xor(tmax[m][r], stp));

      bool ok = true;
#pragma unroll
      for (int m = 0; m < 2; ++m)
#pragma unroll
        for (int r = 0; r < 4; ++r) ok = ok && (tmax[m][r] <= mprev[m][r] + 8.0f);
      const bool skip = __all(ok ? 1 : 0);

      float mnew[2][4], psum[2][4];
#pragma unroll
      for (int m = 0; m < 2; ++m)
#pragma unroll
        for (int r = 0; r < 4; ++r) {
          mnew[m][r] = skip ? mprev[m][r] : fmaxf(mprev[m][r], tmax[m][r]);
          float ps = 0.f;
#pragma unroll
          for (int n = 0; n < 4; ++n) {
            float p = exp2f(s[m][n][r] - mnew[m][r]);
            s[m][n][r] = p;
            ps += p;
          }
          psum[m][r] = ps;
        }
#pragma unroll
      for (int stp = 1; stp <= 8; stp <<= 1)
#pragma unroll
        for (int m = 0; m < 2; ++m)
#pragma unroll
          for (int r = 0; r < 4; ++r)
            psum[m][r] += __shfl_xor(psum[m][r], stp);

#pragma unroll
      for (int m = 0; m < 2; ++m)
#pragma unroll
        for (int r = 0; r < 4; ++r) {
          if (skip) {
            lsum[m][r] += psum[m][r];
          } else {
            float alpha = exp2f(mprev[m][r] - mnew[m][r]);
            lsum[m][r] = lsum[m][r] * alpha + psum[m][r];
            mprev[m][r] = mnew[m][r];
#pragma unroll
            for (int dn = 0; dn < 8; ++dn) o[m][dn][r] *= alpha;
          }
        }

      // ---- P: C/D-frag -> A-operand via per-wave swizzled LDS ----
      unsigned short* Pw = &lds[32768 + wid * 2048];
#pragma unroll
      for (int m = 0; m < 2; ++m)
#pragma unroll
        for (int n = 0; n < 4; ++n)
#pragma unroll
          for (int r = 0; r < 4; ++r) {
            int row = m * 16 + rgrp + r;
            int col = n * 16 + rowA;
            Pw[row * 64 + (col ^ ((row & 7) << 3))] = f2bf(s[m][n][r]);
          }
      // single-wave DS ordering; compiler inserts lgkmcnt waits

      bf16x8 pa[2][2];
#pragma unroll
      for (int m = 0; m < 2; ++m)
#pragma unroll
        for (int kk = 0; kk < 2; ++kk) {
          int row = m * 16 + rowA;
          int col0 = kk * 32 + kgrp;
          pa[m][kk] = *(const bf16x8*)&Pw[row * 64 + (col0 ^ ((row & 7) << 3))];
        }

      // ---- O += P @ V from swizzled LDS ----
      __builtin_amdgcn_s_setprio(1);
#pragma unroll
      for (int kk = 0; kk < 2; ++kk)
#pragma unroll
        for (int dn = 0; dn < 8; ++dn) {
          int row = dn * 16 + rowA;
          int ch  = (kk * 4 + kg) ^ (row & 7);
          bf16x8 vb = *(const bf16x8*)&Vb[row * 64 + ch * 8];
#pragma unroll
          for (int m = 0; m < 2; ++m)
            o[m][dn] = __builtin_amdgcn_mfma_f32_16x16x32_bf16(pa[m][kk], vb, o[m][dn], 0, 0, 0);
        }
      __builtin_amdgcn_s_setprio(0);
    }

    __syncthreads(); // staging drained (vmcnt0) + all reads of cur done
    cur ^= 1;
  }

  // epilogue: normalize (one reciprocal per row) and write bf16 [B,T,C]
  float rinv[2][4];
#pragma unroll
  for (int m = 0; m < 2; ++m)
#pragma unroll
    for (int r = 0; r < 4; ++r) rinv[m][r] = 1.0f / lsum[m][r];
#pragma unroll
  for (int m = 0; m < 2; ++m)
#pragma unroll
    for (int dn = 0; dn < 8; ++dn)
#pragma unroll
      for (int r = 0; r < 4; ++r) {
        float v = o[m][dn][r] * rinv[m][r];
        int t = q0w + m * 16 + rgrp + r;
        int col = h * 128 + dn * 16 + rowA;
        obt[((size_t)b * 2048 + t) * 2048 + col] = f2bf(v);
      }
}

// ---- host launch -----------------------------------------------------------
extern "C" void kernel_launch(void* const* d_in, const int* in_sizes, int n_in,
                              void* d_out, int out_size, void* d_ws, size_t ws_size,
                              hipStream_t stream) {
  const float* x  = (const float*)d_in[0];
  const float* Wq = (const float*)d_in[2];
  const float* Wk = (const float*)d_in[3];
  const float* Wv = (const float*)d_in[4];
  const float* Wo = (const float*)d_in[5];
  float* out = (float*)d_out;

  char* ws = (char*)d_ws;
  unsigned short* xb  = (unsigned short*)(ws + 0);
  unsigned short* wqb = (unsigned short*)(ws + 16777216);
  unsigned short* wkb = (unsigned short*)(ws + 25165824);
  unsigned short* wvb = (unsigned short*)(ws + 33554432);
  unsigned short* wob = (unsigned short*)(ws + 41943040);
  unsigned short* qb  = (unsigned short*)(ws + 50331648);
  unsigned short* kb  = (unsigned short*)(ws + 67108864);
  unsigned short* vtb = (unsigned short*)(ws + 83886080);
  unsigned short* obt = (unsigned short*)(ws + 100663296);
  float* ct = (float*)(ws + 117440512);
  float* st = (float*)(ws + 117964800);

  k_cvt5<<<2048, 256, 0, stream>>>(x, Wq, Wk, Wv, Wo, xb, wqb, wkb, wvb, wob);
  k_rope_tables<<<512, 256, 0, stream>>>(ct, st);
  dim3 gg(16, 32);
  k_gemm<1><<<gg, 256, 0, stream>>>(xb, wqb, (void*)qb,  4096, 2048, 2048);
  k_gemm<1><<<gg, 256, 0, stream>>>(xb, wkb, (void*)kb,  4096, 2048, 2048);
  k_gemm<2><<<gg, 256, 0, stream>>>(xb, wvb, (void*)vtb, 4096, 2048, 2048);
  k_rope<<<16384, 256, 0, stream>>>(qb, kb, ct, st);
  k_flash<<<512, 256, 0, stream>>>(qb, kb, vtb, obt);
  k_gemm<0><<<gg, 256, 0, stream>>>(obt, wob, (void*)out, 4096, 2048, 2048);
}